// Round 1
// baseline (935.537 us; speedup 1.0000x reference)
//
#include <hip/hip_runtime.h>
#include <hip/hip_bf16.h>

typedef short bf16x8_t __attribute__((ext_vector_type(8)));
typedef float f32x4_t __attribute__((ext_vector_type(4)));

#define SDIM 2048
#define DDIM 64
#define QBLK 32
#define KBLK 128
#define NKB  (SDIM / KBLK)

__device__ __forceinline__ unsigned short f2bf(float f) {
    return __builtin_bit_cast(unsigned short, (__bf16)f);
}
__device__ __forceinline__ float bf2f(unsigned short u) {
    unsigned int v = ((unsigned int)u) << 16;
    return __builtin_bit_cast(float, v);
}
__device__ __forceinline__ bf16x8_t pack8(f32x4_t a, f32x4_t b) {
    bf16x8_t r;
    r[0] = (short)f2bf(a[0]); r[1] = (short)f2bf(a[1]);
    r[2] = (short)f2bf(a[2]); r[3] = (short)f2bf(a[3]);
    r[4] = (short)f2bf(b[0]); r[5] = (short)f2bf(b[1]);
    r[6] = (short)f2bf(b[2]); r[7] = (short)f2bf(b[3]);
    return r;
}

__global__ __launch_bounds__(512) void sdpa_fused_kernel(
    const float* __restrict__ Q, const float* __restrict__ K,
    const float* __restrict__ V, float* __restrict__ out,
    float* __restrict__ attn)
{
    __shared__ __align__(16) unsigned short p_blk[QBLK * KBLK];   // 8 KB, swizzled
    __shared__ __align__(16) unsigned short vt_blk[DDIM * KBLK];  // 16 KB, swizzled
    __shared__ float rsum_lds[4][QBLK];
    __shared__ float inv_lds[QBLK];

    const int bid = blockIdx.x;
    const int bh  = bid >> 6;      // 48 (b,h) pairs
    const int qt  = bid & 63;      // 64 q-tiles of 32 rows

    const int tid  = threadIdx.x;
    const int lane = tid & 63;
    const int wv   = tid >> 6;     // 0..7
    const int l15  = lane & 15;
    const int hi   = lane >> 4;    // 0..3
    const int rt   = wv >> 2;      // 0..1 row-tile (16 rows each)
    const int kq   = wv & 3;       // 0..3 key split

    const float* Qb = Q + (size_t)bh * (SDIM * DDIM);
    const float* Kb = K + (size_t)bh * (SDIM * DDIM);
    const float* Vb = V + (size_t)bh * (SDIM * DDIM);
    float* outb  = out  + (size_t)bh * (SDIM * DDIM) + (size_t)qt * QBLK * DDIM;
    float* attnb = attn + (size_t)bh * ((size_t)SDIM * SDIM) + (size_t)qt * QBLK * SDIM;

    const float SC = 0.18033688011112042f;  // (1/sqrt(64)) * log2(e)

    // ---- Q fragments (A operand): rows qt*32 + rt*16 + l15, k-chunks d = c*32 + hi*8 + i
    const float* qp = Qb + (size_t)(qt * QBLK + rt * 16 + l15) * DDIM + hi * 8;
    const bf16x8_t aq0 = pack8(*(const f32x4_t*)qp,        *(const f32x4_t*)(qp + 4));
    const bf16x8_t aq1 = pack8(*(const f32x4_t*)(qp + 32), *(const f32x4_t*)(qp + 36));

    // ================= pass A: row sums of exp(scores) =================
    float rs0 = 0.f, rs1 = 0.f, rs2 = 0.f, rs3 = 0.f;
    {
        const float* kbp = Kb + (size_t)(kq * 512 + l15) * DDIM + hi * 8;
        f32x4_t c0a = *(const f32x4_t*)kbp;
        f32x4_t c0b = *(const f32x4_t*)(kbp + 4);
        f32x4_t c1a = *(const f32x4_t*)(kbp + 32);
        f32x4_t c1b = *(const f32x4_t*)(kbp + 36);
        for (int kt = 0; kt < 32; ++kt) {
            f32x4_t n0a, n0b, n1a, n1b;
            if (kt < 31) {
                const float* np = kbp + (size_t)(kt + 1) * 16 * DDIM;
                n0a = *(const f32x4_t*)np;        n0b = *(const f32x4_t*)(np + 4);
                n1a = *(const f32x4_t*)(np + 32); n1b = *(const f32x4_t*)(np + 36);
            }
            bf16x8_t bk0 = pack8(c0a, c0b);
            bf16x8_t bk1 = pack8(c1a, c1b);
            f32x4_t acc = {0.f, 0.f, 0.f, 0.f};
            acc = __builtin_amdgcn_mfma_f32_16x16x32_bf16(aq0, bk0, acc, 0, 0, 0);
            acc = __builtin_amdgcn_mfma_f32_16x16x32_bf16(aq1, bk1, acc, 0, 0, 0);
            rs0 += exp2f(acc[0] * SC);
            rs1 += exp2f(acc[1] * SC);
            rs2 += exp2f(acc[2] * SC);
            rs3 += exp2f(acc[3] * SC);
            c0a = n0a; c0b = n0b; c1a = n1a; c1b = n1b;
        }
    }
#pragma unroll
    for (int off = 1; off < 16; off <<= 1) {
        rs0 += __shfl_xor(rs0, off);
        rs1 += __shfl_xor(rs1, off);
        rs2 += __shfl_xor(rs2, off);
        rs3 += __shfl_xor(rs3, off);
    }
    if (l15 == 0) {
        rsum_lds[kq][rt * 16 + hi * 4 + 0] = rs0;
        rsum_lds[kq][rt * 16 + hi * 4 + 1] = rs1;
        rsum_lds[kq][rt * 16 + hi * 4 + 2] = rs2;
        rsum_lds[kq][rt * 16 + hi * 4 + 3] = rs3;
    }
    __syncthreads();
    if (tid < QBLK) {
        float t = rsum_lds[0][tid] + rsum_lds[1][tid] + rsum_lds[2][tid] + rsum_lds[3][tid];
        inv_lds[tid] = 1.0f / t;
    }
    __syncthreads();

    // ================= pass B: recompute p, write attn, PV =================
    f32x4_t oacc = {0.f, 0.f, 0.f, 0.f};
    const int dq = wv & 3;  // d col-tile for PV
    for (int kb = 0; kb < NKB; ++kb) {
        const int kbase = kb * KBLK;
        // --- scores for 2 key-tiles -> p_blk (bf16, unnormalized)
#pragma unroll
        for (int t2 = 0; t2 < 2; ++t2) {
            const int kk = kq * 32 + t2 * 16;  // block-local key base
            const float* kp2 = Kb + (size_t)(kbase + kk + l15) * DDIM + hi * 8;
            bf16x8_t bk0 = pack8(*(const f32x4_t*)kp2,        *(const f32x4_t*)(kp2 + 4));
            bf16x8_t bk1 = pack8(*(const f32x4_t*)(kp2 + 32), *(const f32x4_t*)(kp2 + 36));
            f32x4_t acc = {0.f, 0.f, 0.f, 0.f};
            acc = __builtin_amdgcn_mfma_f32_16x16x32_bf16(aq0, bk0, acc, 0, 0, 0);
            acc = __builtin_amdgcn_mfma_f32_16x16x32_bf16(aq1, bk1, acc, 0, 0, 0);
#pragma unroll
            for (int r = 0; r < 4; ++r) {
                const int row = rt * 16 + hi * 4 + r;
                const int col = kk + l15;
                p_blk[row * KBLK + (col ^ ((row & 7) << 3))] = f2bf(exp2f(acc[r] * SC));
            }
        }
        // --- stage V^T (bf16, packed key-pairs, swizzled)
        {
            const int kp_ = tid & 63;
            const int dg  = tid >> 6;
            const float* vp = Vb + (size_t)(kbase + kp_ * 2) * DDIM + dg * 8;
            f32x4_t va0 = *(const f32x4_t*)vp;
            f32x4_t va1 = *(const f32x4_t*)(vp + 4);
            f32x4_t vb0 = *(const f32x4_t*)(vp + DDIM);
            f32x4_t vb1 = *(const f32x4_t*)(vp + DDIM + 4);
#pragma unroll
            for (int j = 0; j < 8; ++j) {
                float fa = (j < 4) ? va0[j] : va1[j - 4];
                float fb = (j < 4) ? vb0[j] : vb1[j - 4];
                unsigned int w = (unsigned int)f2bf(fa) | ((unsigned int)f2bf(fb) << 16);
                const int d = dg * 8 + j;
                *(unsigned int*)&vt_blk[d * KBLK + ((kp_ * 2) ^ ((d & 7) << 3))] = w;
            }
        }
        __syncthreads();
        // --- write normalized attention rows (coalesced float2 per lane)
#pragma unroll
        for (int j = 0; j < 4; ++j) {
            const int row = wv * 4 + j;
            const float inv = inv_lds[row];
            const unsigned int pw =
                *(const unsigned int*)&p_blk[row * KBLK + ((lane * 2) ^ ((row & 7) << 3))];
            float2 o;
            o.x = bf2f((unsigned short)(pw & 0xFFFFu)) * inv;
            o.y = bf2f((unsigned short)(pw >> 16)) * inv;
            *(float2*)(attnb + (size_t)row * SDIM + kbase + lane * 2) = o;
        }
        // --- PV MFMAs (accumulate over all key blocks)
#pragma unroll
        for (int kc = 0; kc < 4; ++kc) {
            const int arow = rt * 16 + l15;
            const int vrow = dq * 16 + l15;
            bf16x8_t ap = *(const bf16x8_t*)
                &p_blk[arow * KBLK + ((kc * 32 + hi * 8) ^ ((arow & 7) << 3))];
            bf16x8_t bv = *(const bf16x8_t*)
                &vt_blk[vrow * KBLK + ((kc * 32 + hi * 8) ^ ((vrow & 7) << 3))];
            oacc = __builtin_amdgcn_mfma_f32_16x16x32_bf16(ap, bv, oacc, 0, 0, 0);
        }
        __syncthreads();
    }
    // --- epilogue: normalized output
#pragma unroll
    for (int r = 0; r < 4; ++r) {
        const int row = rt * 16 + hi * 4 + r;
        outb[(size_t)row * DDIM + dq * 16 + l15] = oacc[r] * inv_lds[row];
    }
}

extern "C" void kernel_launch(void* const* d_in, const int* in_sizes, int n_in,
                              void* d_out, int out_size, void* d_ws, size_t ws_size,
                              hipStream_t stream) {
    const float* Q = (const float*)d_in[0];
    const float* K = (const float*)d_in[1];
    const float* V = (const float*)d_in[2];
    float* out  = (float*)d_out;
    float* attn = out + (size_t)4 * 12 * 2048 * 64;  // output first, then attention

    dim3 grid(48 * 64);
    dim3 block(512);
    sdpa_fused_kernel<<<grid, block, 0, stream>>>(Q, K, V, out, attn);
}

// Round 2
// 600.052 us; speedup vs baseline: 1.5591x; 1.5591x over previous
//
#include <hip/hip_runtime.h>
#include <hip/hip_bf16.h>

typedef short bf16x8_t __attribute__((ext_vector_type(8)));
typedef short short4_t __attribute__((ext_vector_type(4)));
typedef float f32x4_t __attribute__((ext_vector_type(4)));

#define SDIM 2048
#define DDIM 64
#define QBLK 32
#define KBLK 128
#define NKB  (SDIM / KBLK)
#define NBH  48

__device__ __forceinline__ unsigned short f2bf(float f) {
    return __builtin_bit_cast(unsigned short, (__bf16)f);
}
__device__ __forceinline__ float bf2f(unsigned short u) {
    unsigned int v = ((unsigned int)u) << 16;
    return __builtin_bit_cast(float, v);
}
__device__ __forceinline__ bf16x8_t pack8(f32x4_t a, f32x4_t b) {
    bf16x8_t r;
    r[0] = (short)f2bf(a[0]); r[1] = (short)f2bf(a[1]);
    r[2] = (short)f2bf(a[2]); r[3] = (short)f2bf(a[3]);
    r[4] = (short)f2bf(b[0]); r[5] = (short)f2bf(b[1]);
    r[6] = (short)f2bf(b[2]); r[7] = (short)f2bf(b[3]);
    return r;
}

// ---------- prep 1: K fp32 -> bf16 (row-major, same layout) ----------
__global__ __launch_bounds__(256) void cvt_k_kernel(const float* __restrict__ K,
                                                    unsigned short* __restrict__ Kb) {
    size_t i = ((size_t)blockIdx.x * 256 + threadIdx.x) * 8;
    f32x4_t a = *(const f32x4_t*)(K + i);
    f32x4_t b = *(const f32x4_t*)(K + i + 4);
    *(bf16x8_t*)(Kb + i) = pack8(a, b);
}

// ---------- prep 2: V fp32 [bh][k][d] -> bf16 V^T [bh][d][k] ----------
__global__ __launch_bounds__(256) void tr_v_kernel(const float* __restrict__ V,
                                                   unsigned short* __restrict__ VT) {
    __shared__ unsigned short lt[64 * 72];  // 64 d-rows x 64 k, stride 72 (pad)
    const int bh = blockIdx.x >> 5;   // 48
    const int kt = blockIdx.x & 31;   // 32 k-tiles of 64
    const float* Vb = V + (size_t)bh * (SDIM * DDIM) + (size_t)kt * 64 * DDIM;
    unsigned short* VTb = VT + (size_t)bh * (DDIM * SDIM) + kt * 64;
    const int t = threadIdx.x;
    {
        const int kl = t >> 2, dg = t & 3;
        const float* vp = Vb + kl * DDIM + dg * 16;
        f32x4_t v0 = *(const f32x4_t*)vp;
        f32x4_t v1 = *(const f32x4_t*)(vp + 4);
        f32x4_t v2 = *(const f32x4_t*)(vp + 8);
        f32x4_t v3 = *(const f32x4_t*)(vp + 12);
#pragma unroll
        for (int j = 0; j < 16; ++j) {
            float f = (j < 4) ? v0[j] : (j < 8) ? v1[j - 4] : (j < 12) ? v2[j - 8] : v3[j - 12];
            lt[(dg * 16 + j) * 72 + kl] = f2bf(f);
        }
    }
    __syncthreads();
    {
        const int d = t >> 2, kg = t & 3;
        bf16x8_t w0 = *(const bf16x8_t*)&lt[d * 72 + kg * 16];
        bf16x8_t w1 = *(const bf16x8_t*)&lt[d * 72 + kg * 16 + 8];
        *(bf16x8_t*)(VTb + (size_t)d * SDIM + kg * 16) = w0;
        *(bf16x8_t*)(VTb + (size_t)d * SDIM + kg * 16 + 8) = w1;
    }
}

// ---------- main fused kernel ----------
__global__ __launch_bounds__(512) void sdpa_main_kernel(
    const float* __restrict__ Q, const unsigned short* __restrict__ Kb,
    const unsigned short* __restrict__ VT, float* __restrict__ out,
    float* __restrict__ attn)
{
    __shared__ __align__(16) unsigned short p_blk[2][QBLK * KBLK];  // 2 x 8 KB, swizzled, normalized
    __shared__ float red_lds[4][QBLK];
    __shared__ float lg2_lds[QBLK];

    const int bid = blockIdx.x;
    const int bh  = bid >> 6;
    const int qt  = bid & 63;

    const int tid  = threadIdx.x;
    const int lane = tid & 63;
    const int wv   = tid >> 6;     // 0..7
    const int l15  = lane & 15;
    const int hi   = lane >> 4;    // 0..3
    const int rt   = wv >> 2;      // 0..1 (16-row tile)
    const int kq   = wv & 3;       // 0..3 (key split / d-col split)

    const unsigned short* KbB = Kb + (size_t)bh * (SDIM * DDIM);
    const unsigned short* VTb = VT + (size_t)bh * (DDIM * SDIM);
    float* outb  = out  + (size_t)bh * (SDIM * DDIM) + (size_t)qt * QBLK * DDIM;
    float* attnb = attn + (size_t)bh * ((size_t)SDIM * SDIM) + (size_t)qt * QBLK * SDIM;

    const float SC = 0.18033688011112042f;  // (1/sqrt(64)) * log2(e)

    // ---- Q fragments (A operand)
    const float* qp = Q + ((size_t)bh * SDIM + qt * QBLK + rt * 16 + l15) * DDIM + hi * 8;
    const bf16x8_t aq0 = pack8(*(const f32x4_t*)qp,        *(const f32x4_t*)(qp + 4));
    const bf16x8_t aq1 = pack8(*(const f32x4_t*)(qp + 32), *(const f32x4_t*)(qp + 36));

    // ================= pass A: row sums of exp2(s*SC) =================
    float rs0 = 0.f, rs1 = 0.f, rs2 = 0.f, rs3 = 0.f;
    {
        const unsigned short* kbp = KbB + (size_t)(kq * 512 + l15) * DDIM + hi * 8;
        bf16x8_t c0 = *(const bf16x8_t*)kbp;
        bf16x8_t c1 = *(const bf16x8_t*)(kbp + 32);
        for (int kt = 0; kt < 32; ++kt) {
            bf16x8_t n0, n1;
            if (kt < 31) {
                const unsigned short* np = kbp + (size_t)(kt + 1) * 16 * DDIM;
                n0 = *(const bf16x8_t*)np;
                n1 = *(const bf16x8_t*)(np + 32);
            }
            f32x4_t acc = {0.f, 0.f, 0.f, 0.f};
            acc = __builtin_amdgcn_mfma_f32_16x16x32_bf16(aq0, c0, acc, 0, 0, 0);
            acc = __builtin_amdgcn_mfma_f32_16x16x32_bf16(aq1, c1, acc, 0, 0, 0);
            rs0 += __builtin_amdgcn_exp2f(acc[0] * SC);
            rs1 += __builtin_amdgcn_exp2f(acc[1] * SC);
            rs2 += __builtin_amdgcn_exp2f(acc[2] * SC);
            rs3 += __builtin_amdgcn_exp2f(acc[3] * SC);
            c0 = n0; c1 = n1;
        }
    }
#pragma unroll
    for (int off = 1; off < 16; off <<= 1) {
        rs0 += __shfl_xor(rs0, off);
        rs1 += __shfl_xor(rs1, off);
        rs2 += __shfl_xor(rs2, off);
        rs3 += __shfl_xor(rs3, off);
    }
    if (l15 == 0) {
        red_lds[kq][rt * 16 + hi * 4 + 0] = rs0;
        red_lds[kq][rt * 16 + hi * 4 + 1] = rs1;
        red_lds[kq][rt * 16 + hi * 4 + 2] = rs2;
        red_lds[kq][rt * 16 + hi * 4 + 3] = rs3;
    }
    __syncthreads();
    if (tid < QBLK) {
        float t = red_lds[0][tid] + red_lds[1][tid] + red_lds[2][tid] + red_lds[3][tid];
        lg2_lds[tid] = __builtin_amdgcn_logf(t);  // v_log_f32 = log2
    }
    __syncthreads();

    float nlg[4];
#pragma unroll
    for (int r = 0; r < 4; ++r) nlg[r] = lg2_lds[rt * 16 + hi * 4 + r];

    // ================= pass B: recompute p (normalized), write attn, PV =================
    f32x4_t oacc = {0.f, 0.f, 0.f, 0.f};
    for (int kb = 0; kb < NKB; ++kb) {
        const int kbase = kb * KBLK;
        unsigned short* pb = p_blk[kb & 1];
        // --- scores -> normalized p (bf16) into swizzled LDS
#pragma unroll
        for (int t2 = 0; t2 < 2; ++t2) {
            const int kk = kq * 32 + t2 * 16;
            const unsigned short* kp2 = KbB + (size_t)(kbase + kk + l15) * DDIM + hi * 8;
            bf16x8_t b0 = *(const bf16x8_t*)kp2;
            bf16x8_t b1 = *(const bf16x8_t*)(kp2 + 32);
            f32x4_t acc = {0.f, 0.f, 0.f, 0.f};
            acc = __builtin_amdgcn_mfma_f32_16x16x32_bf16(aq0, b0, acc, 0, 0, 0);
            acc = __builtin_amdgcn_mfma_f32_16x16x32_bf16(aq1, b1, acc, 0, 0, 0);
#pragma unroll
            for (int r = 0; r < 4; ++r) {
                const int row = rt * 16 + hi * 4 + r;
                const int col = kk + l15;
                float p = __builtin_amdgcn_exp2f(__builtin_fmaf(acc[r], SC, -nlg[r]));
                pb[row * KBLK + (col ^ ((row & 15) << 3))] = f2bf(p);
            }
        }
        __syncthreads();
        // --- attn store: float4/lane, 2 rows per wave-op
#pragma unroll
        for (int j2 = 0; j2 < 2; ++j2) {
            const int row = wv * 4 + j2 * 2 + (lane >> 5);
            const int l31 = lane & 31;
            const short4_t pv =
                *(const short4_t*)&pb[row * KBLK + ((l31 * 4) ^ ((row & 15) << 3))];
            float4 o;
            o.x = bf2f((unsigned short)pv[0]);
            o.y = bf2f((unsigned short)pv[1]);
            o.z = bf2f((unsigned short)pv[2]);
            o.w = bf2f((unsigned short)pv[3]);
            *(float4*)(attnb + (size_t)row * SDIM + kbase + l31 * 4) = o;
        }
        // --- PV: A from LDS, B directly from global V^T (L2-resident)
        {
            const int arow = rt * 16 + l15;
            const unsigned short* vrow = VTb + (size_t)(kq * 16 + l15) * SDIM + kbase;
#pragma unroll
            for (int kc = 0; kc < 4; ++kc) {
                bf16x8_t ap = *(const bf16x8_t*)
                    &pb[arow * KBLK + ((kc * 32 + hi * 8) ^ ((arow & 15) << 3))];
                bf16x8_t bv = *(const bf16x8_t*)(vrow + kc * 32 + hi * 8);
                oacc = __builtin_amdgcn_mfma_f32_16x16x32_bf16(ap, bv, oacc, 0, 0, 0);
            }
        }
        __syncthreads();  // protects pb[(kb+1)&1] writers vs this buf's consumers? No:
                          // single barrier per iter is safe w/ double buffer; this IS that barrier.
    }
    // --- epilogue (already normalized)
#pragma unroll
    for (int r = 0; r < 4; ++r) {
        const int row = rt * 16 + hi * 4 + r;
        outb[(size_t)row * DDIM + kq * 16 + l15] = oacc[r];
    }
}

extern "C" void kernel_launch(void* const* d_in, const int* in_sizes, int n_in,
                              void* d_out, int out_size, void* d_ws, size_t ws_size,
                              hipStream_t stream) {
    const float* Q = (const float*)d_in[0];
    const float* K = (const float*)d_in[1];
    const float* V = (const float*)d_in[2];
    float* out  = (float*)d_out;
    float* attn = out + (size_t)NBH * SDIM * DDIM;

    unsigned short* Kb = (unsigned short*)d_ws;
    unsigned short* VT = Kb + (size_t)NBH * SDIM * DDIM;

    // prep: convert K, transpose+convert V
    cvt_k_kernel<<<dim3((NBH * SDIM * DDIM) / (256 * 8)), dim3(256), 0, stream>>>(K, Kb);
    tr_v_kernel<<<dim3(NBH * 32), dim3(256), 0, stream>>>(V, VT);

    sdpa_main_kernel<<<dim3(NBH * 64), dim3(512), 0, stream>>>(Q, Kb, VT, out, attn);
}

// Round 3
// 565.859 us; speedup vs baseline: 1.6533x; 1.0604x over previous
//
#include <hip/hip_runtime.h>
#include <hip/hip_bf16.h>

typedef short bf16x8_t __attribute__((ext_vector_type(8)));
typedef short short4_t __attribute__((ext_vector_type(4)));
typedef float f32x4_t __attribute__((ext_vector_type(4)));

#define SDIM 2048
#define DDIM 64
#define QBLK 32
#define KBLK 128
#define NKB  (SDIM / KBLK)
#define NBH  48

__device__ __forceinline__ unsigned short f2bf(float f) {
    return __builtin_bit_cast(unsigned short, (__bf16)f);
}
__device__ __forceinline__ float bf2f(unsigned short u) {
    unsigned int v = ((unsigned int)u) << 16;
    return __builtin_bit_cast(float, v);
}
__device__ __forceinline__ bf16x8_t pack8(f32x4_t a, f32x4_t b) {
    bf16x8_t r;
    r[0] = (short)f2bf(a[0]); r[1] = (short)f2bf(a[1]);
    r[2] = (short)f2bf(a[2]); r[3] = (short)f2bf(a[3]);
    r[4] = (short)f2bf(b[0]); r[5] = (short)f2bf(b[1]);
    r[6] = (short)f2bf(b[2]); r[7] = (short)f2bf(b[3]);
    return r;
}

// LDS-only block sync: drains LDS ops, leaves global loads/stores in flight.
__device__ __forceinline__ void lds_sync() {
    asm volatile("s_waitcnt lgkmcnt(0)" ::: "memory");
    __builtin_amdgcn_s_barrier();
    asm volatile("" ::: "memory");
}

// ---------- prep 1: K fp32 -> bf16 (row-major) ----------
__global__ __launch_bounds__(256) void cvt_k_kernel(const float* __restrict__ K,
                                                    unsigned short* __restrict__ Kb) {
    size_t i = ((size_t)blockIdx.x * 256 + threadIdx.x) * 8;
    f32x4_t a = *(const f32x4_t*)(K + i);
    f32x4_t b = *(const f32x4_t*)(K + i + 4);
    *(bf16x8_t*)(Kb + i) = pack8(a, b);
}

// ---------- prep 2: V fp32 [bh][k][d] -> bf16 V^T [bh][d][k] ----------
__global__ __launch_bounds__(256) void tr_v_kernel(const float* __restrict__ V,
                                                   unsigned short* __restrict__ VT) {
    __shared__ unsigned short lt[64 * 72];
    const int bh = blockIdx.x >> 5;
    const int kt = blockIdx.x & 31;
    const float* Vb = V + (size_t)bh * (SDIM * DDIM) + (size_t)kt * 64 * DDIM;
    unsigned short* VTb = VT + (size_t)bh * (DDIM * SDIM) + kt * 64;
    const int t = threadIdx.x;
    {
        const int kl = t >> 2, dg = t & 3;
        const float* vp = Vb + kl * DDIM + dg * 16;
        f32x4_t v0 = *(const f32x4_t*)vp;
        f32x4_t v1 = *(const f32x4_t*)(vp + 4);
        f32x4_t v2 = *(const f32x4_t*)(vp + 8);
        f32x4_t v3 = *(const f32x4_t*)(vp + 12);
#pragma unroll
        for (int j = 0; j < 16; ++j) {
            float f = (j < 4) ? v0[j] : (j < 8) ? v1[j - 4] : (j < 12) ? v2[j - 8] : v3[j - 12];
            lt[(dg * 16 + j) * 72 + kl] = f2bf(f);
        }
    }
    __syncthreads();
    {
        const int d = t >> 2, kg = t & 3;
        bf16x8_t w0 = *(const bf16x8_t*)&lt[d * 72 + kg * 16];
        bf16x8_t w1 = *(const bf16x8_t*)&lt[d * 72 + kg * 16 + 8];
        *(bf16x8_t*)(VTb + (size_t)d * SDIM + kg * 16) = w0;
        *(bf16x8_t*)(VTb + (size_t)d * SDIM + kg * 16 + 8) = w1;
    }
}

// ---------- main fused kernel ----------
__global__ __launch_bounds__(512) void sdpa_main_kernel(
    const float* __restrict__ Q, const unsigned short* __restrict__ Kb,
    const unsigned short* __restrict__ VT, float* __restrict__ out,
    float* __restrict__ attn)
{
    __shared__ __align__(16) unsigned short p_blk[2][QBLK * KBLK];  // normalized p, swizzled
    __shared__ float red_lds[4][QBLK];
    __shared__ float lg2_lds[QBLK];

    const int bid = blockIdx.x;
    const int bh  = bid >> 6;
    const int qt  = bid & 63;

    const int tid  = threadIdx.x;
    const int lane = tid & 63;
    const int wv   = tid >> 6;
    const int l15  = lane & 15;
    const int hi   = lane >> 4;
    const int rt   = wv >> 2;
    const int kq   = wv & 3;

    const unsigned short* KbB = Kb + (size_t)bh * (SDIM * DDIM);
    const unsigned short* VTb = VT + (size_t)bh * (DDIM * SDIM);
    float* outb  = out  + (size_t)bh * (SDIM * DDIM) + (size_t)qt * QBLK * DDIM;
    float* attnb = attn + (size_t)bh * ((size_t)SDIM * SDIM) + (size_t)qt * QBLK * SDIM;

    const float SC = 0.18033688011112042f;  // (1/sqrt(64)) * log2(e)

    // ---- Q fragments
    const float* qp = Q + ((size_t)bh * SDIM + qt * QBLK + rt * 16 + l15) * DDIM + hi * 8;
    const bf16x8_t aq0 = pack8(*(const f32x4_t*)qp,        *(const f32x4_t*)(qp + 4));
    const bf16x8_t aq1 = pack8(*(const f32x4_t*)(qp + 32), *(const f32x4_t*)(qp + 36));

    // ================= pass A: row sums of exp2(s*SC) =================
    float rs0 = 0.f, rs1 = 0.f, rs2 = 0.f, rs3 = 0.f;
    {
        const unsigned short* kbp = KbB + (size_t)(kq * 512 + l15) * DDIM + hi * 8;
        bf16x8_t c0 = *(const bf16x8_t*)kbp;
        bf16x8_t c1 = *(const bf16x8_t*)(kbp + 32);
        for (int kt = 0; kt < 32; ++kt) {
            bf16x8_t n0, n1;
            if (kt < 31) {
                const unsigned short* np = kbp + (size_t)(kt + 1) * 16 * DDIM;
                n0 = *(const bf16x8_t*)np;
                n1 = *(const bf16x8_t*)(np + 32);
            }
            f32x4_t acc = {0.f, 0.f, 0.f, 0.f};
            acc = __builtin_amdgcn_mfma_f32_16x16x32_bf16(aq0, c0, acc, 0, 0, 0);
            acc = __builtin_amdgcn_mfma_f32_16x16x32_bf16(aq1, c1, acc, 0, 0, 0);
            rs0 += __builtin_amdgcn_exp2f(acc[0] * SC);
            rs1 += __builtin_amdgcn_exp2f(acc[1] * SC);
            rs2 += __builtin_amdgcn_exp2f(acc[2] * SC);
            rs3 += __builtin_amdgcn_exp2f(acc[3] * SC);
            c0 = n0; c1 = n1;
        }
    }
#pragma unroll
    for (int off = 1; off < 16; off <<= 1) {
        rs0 += __shfl_xor(rs0, off);
        rs1 += __shfl_xor(rs1, off);
        rs2 += __shfl_xor(rs2, off);
        rs3 += __shfl_xor(rs3, off);
    }
    if (l15 == 0) {
        red_lds[kq][rt * 16 + hi * 4 + 0] = rs0;
        red_lds[kq][rt * 16 + hi * 4 + 1] = rs1;
        red_lds[kq][rt * 16 + hi * 4 + 2] = rs2;
        red_lds[kq][rt * 16 + hi * 4 + 3] = rs3;
    }
    __syncthreads();
    if (tid < QBLK) {
        float t = red_lds[0][tid] + red_lds[1][tid] + red_lds[2][tid] + red_lds[3][tid];
        lg2_lds[tid] = __builtin_amdgcn_logf(t);  // v_log_f32 = log2
    }
    __syncthreads();

    float nlg[4];
#pragma unroll
    for (int r = 0; r < 4; ++r) nlg[r] = lg2_lds[rt * 16 + hi * 4 + r];

    // ================= pass B =================
    f32x4_t oacc = {0.f, 0.f, 0.f, 0.f};

    // produce p for k-block kb into dst (normalized, swizzled)
    auto produce_p = [&](unsigned short* dst, bf16x8_t kA0, bf16x8_t kA1,
                         bf16x8_t kB0, bf16x8_t kB1) {
        f32x4_t a0 = {0.f, 0.f, 0.f, 0.f}, a1 = {0.f, 0.f, 0.f, 0.f};
        a0 = __builtin_amdgcn_mfma_f32_16x16x32_bf16(aq0, kA0, a0, 0, 0, 0);
        a0 = __builtin_amdgcn_mfma_f32_16x16x32_bf16(aq1, kA1, a0, 0, 0, 0);
        a1 = __builtin_amdgcn_mfma_f32_16x16x32_bf16(aq0, kB0, a1, 0, 0, 0);
        a1 = __builtin_amdgcn_mfma_f32_16x16x32_bf16(aq1, kB1, a1, 0, 0, 0);
#pragma unroll
        for (int r = 0; r < 4; ++r) {
            const int row = rt * 16 + hi * 4 + r;
            const int swz = (row & 15) << 3;
            const int c0  = kq * 32 + l15;
            dst[row * KBLK + (c0 ^ swz)] =
                f2bf(__builtin_amdgcn_exp2f(__builtin_fmaf(a0[r], SC, -nlg[r])));
            dst[row * KBLK + ((c0 + 16) ^ swz)] =
                f2bf(__builtin_amdgcn_exp2f(__builtin_fmaf(a1[r], SC, -nlg[r])));
        }
    };

    // consume p for k-block: attn store + PV accumulate
    auto consume = [&](const unsigned short* cur, int kbase,
                       bf16x8_t v0, bf16x8_t v1, bf16x8_t v2, bf16x8_t v3) {
#pragma unroll
        for (int j2 = 0; j2 < 2; ++j2) {
            const int row = wv * 4 + j2 * 2 + (lane >> 5);
            const int l31 = lane & 31;
            const short4_t pv =
                *(const short4_t*)&cur[row * KBLK + ((l31 * 4) ^ ((row & 15) << 3))];
            f32x4_t o;
            o[0] = bf2f((unsigned short)pv[0]);
            o[1] = bf2f((unsigned short)pv[1]);
            o[2] = bf2f((unsigned short)pv[2]);
            o[3] = bf2f((unsigned short)pv[3]);
            __builtin_nontemporal_store(
                o, (f32x4_t*)(attnb + (size_t)row * SDIM + kbase + l31 * 4));
        }
        const int arow = rt * 16 + l15;
        const int aswz = (arow & 15) << 3;
        oacc = __builtin_amdgcn_mfma_f32_16x16x32_bf16(
            *(const bf16x8_t*)&cur[arow * KBLK + ((hi * 8) ^ aswz)], v0, oacc, 0, 0, 0);
        oacc = __builtin_amdgcn_mfma_f32_16x16x32_bf16(
            *(const bf16x8_t*)&cur[arow * KBLK + ((32 + hi * 8) ^ aswz)], v1, oacc, 0, 0, 0);
        oacc = __builtin_amdgcn_mfma_f32_16x16x32_bf16(
            *(const bf16x8_t*)&cur[arow * KBLK + ((64 + hi * 8) ^ aswz)], v2, oacc, 0, 0, 0);
        oacc = __builtin_amdgcn_mfma_f32_16x16x32_bf16(
            *(const bf16x8_t*)&cur[arow * KBLK + ((96 + hi * 8) ^ aswz)], v3, oacc, 0, 0, 0);
    };

    // prologue: p for kb=0
    {
        const unsigned short* kp = KbB + (size_t)(kq * 32 + l15) * DDIM + hi * 8;
        produce_p(p_blk[0],
                  *(const bf16x8_t*)kp, *(const bf16x8_t*)(kp + 32),
                  *(const bf16x8_t*)(kp + 16 * DDIM), *(const bf16x8_t*)(kp + 16 * DDIM + 32));
    }
    lds_sync();

    for (int kb = 0; kb < NKB - 1; ++kb) {
        unsigned short* cur = p_blk[kb & 1];
        unsigned short* nxt = p_blk[(kb + 1) & 1];
        const int kbase = kb * KBLK;
        // K prefetch for kb+1
        const unsigned short* kp =
            KbB + (size_t)(kbase + KBLK + kq * 32 + l15) * DDIM + hi * 8;
        const bf16x8_t kA0 = *(const bf16x8_t*)kp;
        const bf16x8_t kA1 = *(const bf16x8_t*)(kp + 32);
        const bf16x8_t kB0 = *(const bf16x8_t*)(kp + 16 * DDIM);
        const bf16x8_t kB1 = *(const bf16x8_t*)(kp + 16 * DDIM + 32);
        // V loads for kb
        const unsigned short* vp = VTb + (size_t)(kq * 16 + l15) * SDIM + kbase + hi * 8;
        const bf16x8_t v0 = *(const bf16x8_t*)vp;
        const bf16x8_t v1 = *(const bf16x8_t*)(vp + 32);
        const bf16x8_t v2 = *(const bf16x8_t*)(vp + 64);
        const bf16x8_t v3 = *(const bf16x8_t*)(vp + 96);

        consume(cur, kbase, v0, v1, v2, v3);
        produce_p(nxt, kA0, kA1, kB0, kB1);
        lds_sync();
    }
    // final block: consume only
    {
        const int kbase = (NKB - 1) * KBLK;
        const unsigned short* cur = p_blk[(NKB - 1) & 1];
        const unsigned short* vp = VTb + (size_t)(kq * 16 + l15) * SDIM + kbase + hi * 8;
        consume(cur, kbase,
                *(const bf16x8_t*)vp, *(const bf16x8_t*)(vp + 32),
                *(const bf16x8_t*)(vp + 64), *(const bf16x8_t*)(vp + 96));
    }

    // --- epilogue (already normalized)
#pragma unroll
    for (int r = 0; r < 4; ++r) {
        const int row = rt * 16 + hi * 4 + r;
        outb[(size_t)row * DDIM + kq * 16 + l15] = oacc[r];
    }
}

extern "C" void kernel_launch(void* const* d_in, const int* in_sizes, int n_in,
                              void* d_out, int out_size, void* d_ws, size_t ws_size,
                              hipStream_t stream) {
    const float* Q = (const float*)d_in[0];
    const float* K = (const float*)d_in[1];
    const float* V = (const float*)d_in[2];
    float* out  = (float*)d_out;
    float* attn = out + (size_t)NBH * SDIM * DDIM;

    unsigned short* Kb = (unsigned short*)d_ws;
    unsigned short* VT = Kb + (size_t)NBH * SDIM * DDIM;

    cvt_k_kernel<<<dim3((NBH * SDIM * DDIM) / (256 * 8)), dim3(256), 0, stream>>>(K, Kb);
    tr_v_kernel<<<dim3(NBH * 32), dim3(256), 0, stream>>>(V, VT);

    sdpa_main_kernel<<<dim3(NBH * 64), dim3(512), 0, stream>>>(Q, Kb, VT, out, attn);
}

// Round 4
// 552.322 us; speedup vs baseline: 1.6938x; 1.0245x over previous
//
#include <hip/hip_runtime.h>
#include <hip/hip_bf16.h>

typedef short bf16x8_t __attribute__((ext_vector_type(8)));
typedef short short4_t __attribute__((ext_vector_type(4)));
typedef float f32x4_t __attribute__((ext_vector_type(4)));

#define SDIM 2048
#define DDIM 64
#define KBLK 128
#define NKB  (SDIM / KBLK)
#define NBH  48

__device__ __forceinline__ unsigned short f2bf(float f) {
    return __builtin_bit_cast(unsigned short, (__bf16)f);
}
__device__ __forceinline__ float bf2f(unsigned short u) {
    unsigned int v = ((unsigned int)u) << 16;
    return __builtin_bit_cast(float, v);
}
__device__ __forceinline__ bf16x8_t pack8(f32x4_t a, f32x4_t b) {
    bf16x8_t r;
    r[0] = (short)f2bf(a[0]); r[1] = (short)f2bf(a[1]);
    r[2] = (short)f2bf(a[2]); r[3] = (short)f2bf(a[3]);
    r[4] = (short)f2bf(b[0]); r[5] = (short)f2bf(b[1]);
    r[6] = (short)f2bf(b[2]); r[7] = (short)f2bf(b[3]);
    return r;
}
__device__ __forceinline__ bf16x8_t pack8s(f32x4_t a, f32x4_t b, float s) {
    bf16x8_t r;
    r[0] = (short)f2bf(a[0] * s); r[1] = (short)f2bf(a[1] * s);
    r[2] = (short)f2bf(a[2] * s); r[3] = (short)f2bf(a[3] * s);
    r[4] = (short)f2bf(b[0] * s); r[5] = (short)f2bf(b[1] * s);
    r[6] = (short)f2bf(b[2] * s); r[7] = (short)f2bf(b[3] * s);
    return r;
}

// ---------- prep 1: K fp32 -> bf16 (row-major) ----------
__global__ __launch_bounds__(256) void cvt_k_kernel(const float* __restrict__ K,
                                                    unsigned short* __restrict__ Kb) {
    size_t i = ((size_t)blockIdx.x * 256 + threadIdx.x) * 8;
    f32x4_t a = *(const f32x4_t*)(K + i);
    f32x4_t b = *(const f32x4_t*)(K + i + 4);
    *(bf16x8_t*)(Kb + i) = pack8(a, b);
}

// ---------- prep 2: V fp32 [bh][k][d] -> bf16 V^T [bh][d][k] ----------
__global__ __launch_bounds__(256) void tr_v_kernel(const float* __restrict__ V,
                                                   unsigned short* __restrict__ VT) {
    __shared__ unsigned short lt[64 * 72];
    const int bh = blockIdx.x >> 5;
    const int kt = blockIdx.x & 31;
    const float* Vb = V + (size_t)bh * (SDIM * DDIM) + (size_t)kt * 64 * DDIM;
    unsigned short* VTb = VT + (size_t)bh * (DDIM * SDIM) + kt * 64;
    const int t = threadIdx.x;
    {
        const int kl = t >> 2, dg = t & 3;
        const float* vp = Vb + kl * DDIM + dg * 16;
        f32x4_t v0 = *(const f32x4_t*)vp;
        f32x4_t v1 = *(const f32x4_t*)(vp + 4);
        f32x4_t v2 = *(const f32x4_t*)(vp + 8);
        f32x4_t v3 = *(const f32x4_t*)(vp + 12);
#pragma unroll
        for (int j = 0; j < 16; ++j) {
            float f = (j < 4) ? v0[j] : (j < 8) ? v1[j - 4] : (j < 12) ? v2[j - 8] : v3[j - 12];
            lt[(dg * 16 + j) * 72 + kl] = f2bf(f);
        }
    }
    __syncthreads();
    {
        const int d = t >> 2, kg = t & 3;
        bf16x8_t w0 = *(const bf16x8_t*)&lt[d * 72 + kg * 16];
        bf16x8_t w1 = *(const bf16x8_t*)&lt[d * 72 + kg * 16 + 8];
        *(bf16x8_t*)(VTb + (size_t)d * SDIM + kg * 16) = w0;
        *(bf16x8_t*)(VTb + (size_t)d * SDIM + kg * 16 + 8) = w1;
    }
}

// ---------- main fused kernel: one wave owns 16 q-rows, ZERO barriers ----------
__global__ __launch_bounds__(256) void sdpa_main_kernel(
    const float* __restrict__ Q, const unsigned short* __restrict__ Kb,
    const unsigned short* __restrict__ VT, float* __restrict__ out,
    float* __restrict__ attn)
{
    __shared__ __align__(16) unsigned short p_lds[4][16 * KBLK];  // 4 KB per wave, private

    const int bid = blockIdx.x;
    const int bh  = bid >> 5;
    const int qt  = bid & 31;
    const int tid = threadIdx.x;
    const int lane = tid & 63;
    const int wv   = tid >> 6;     // 0..3
    const int l15  = lane & 15;
    const int hi   = lane >> 4;    // 0..3
    const int qbase = qt * 64 + wv * 16;

    const unsigned short* KbB = Kb + (size_t)bh * (SDIM * DDIM);
    const unsigned short* VTb = VT + (size_t)bh * (DDIM * SDIM);
    float* outW  = out  + ((size_t)bh * SDIM + qbase) * DDIM;
    float* attnW = attn + (size_t)bh * SDIM * SDIM + (size_t)qbase * SDIM;
    unsigned short* pw = p_lds[wv];

    const float SC = 0.18033688011112042f;  // (1/sqrt(64)) * log2(e)

    // ---- Q fragments, pre-scaled by SC
    const float* qp = Q + ((size_t)bh * SDIM + qbase + l15) * DDIM + hi * 8;
    const bf16x8_t aq0 = pack8s(*(const f32x4_t*)qp,        *(const f32x4_t*)(qp + 4), SC);
    const bf16x8_t aq1 = pack8s(*(const f32x4_t*)(qp + 32), *(const f32x4_t*)(qp + 36), SC);

    // ================= pass A: row sums of 2^(s*SC), wave-local =================
    float rs[4] = {0.f, 0.f, 0.f, 0.f};
    {
        const unsigned short* kp = KbB + (size_t)l15 * DDIM + hi * 8;
        const size_t r16 = (size_t)16 * DDIM;
        bf16x8_t c0 = *(const bf16x8_t*)kp;
        bf16x8_t c1 = *(const bf16x8_t*)(kp + 32);
        bf16x8_t c2 = *(const bf16x8_t*)(kp + r16);
        bf16x8_t c3 = *(const bf16x8_t*)(kp + r16 + 32);
        for (int ci = 0; ci < 64; ++ci) {       // 32 k-cols per iter
            bf16x8_t n0 = c0, n1 = c1, n2 = c2, n3 = c3;
            if (ci < 63) {
                const unsigned short* np = kp + (size_t)(ci + 1) * 32 * DDIM;
                n0 = *(const bf16x8_t*)np;
                n1 = *(const bf16x8_t*)(np + 32);
                n2 = *(const bf16x8_t*)(np + r16);
                n3 = *(const bf16x8_t*)(np + r16 + 32);
            }
            f32x4_t a0 = {0.f, 0.f, 0.f, 0.f}, a1 = {0.f, 0.f, 0.f, 0.f};
            a0 = __builtin_amdgcn_mfma_f32_16x16x32_bf16(aq0, c0, a0, 0, 0, 0);
            a0 = __builtin_amdgcn_mfma_f32_16x16x32_bf16(aq1, c1, a0, 0, 0, 0);
            a1 = __builtin_amdgcn_mfma_f32_16x16x32_bf16(aq0, c2, a1, 0, 0, 0);
            a1 = __builtin_amdgcn_mfma_f32_16x16x32_bf16(aq1, c3, a1, 0, 0, 0);
#pragma unroll
            for (int r = 0; r < 4; ++r)
                rs[r] += __builtin_amdgcn_exp2f(a0[r]) + __builtin_amdgcn_exp2f(a1[r]);
            c0 = n0; c1 = n1; c2 = n2; c3 = n3;
        }
    }
#pragma unroll
    for (int off = 1; off < 16; off <<= 1) {
#pragma unroll
        for (int r = 0; r < 4; ++r) rs[r] += __shfl_xor(rs[r], off);
    }
    float nlg[4];
#pragma unroll
    for (int r = 0; r < 4; ++r) nlg[r] = __builtin_amdgcn_logf(rs[r]);  // log2

    // ================= pass B: per k-block produce p, store attn, PV =================
    f32x4_t oacc[4] = {{0.f,0.f,0.f,0.f},{0.f,0.f,0.f,0.f},{0.f,0.f,0.f,0.f},{0.f,0.f,0.f,0.f}};

    for (int kb = 0; kb < NKB; ++kb) {
        const int kbase = kb * KBLK;
        const unsigned short* vbase = VTb + kbase + hi * 8;

        // issue V dt=0 loads early (consumed after produce)
        bf16x8_t bv[4];
#pragma unroll
        for (int kc = 0; kc < 4; ++kc)
            bv[kc] = *(const bf16x8_t*)(vbase + (size_t)l15 * SDIM + kc * 32);

        // --- produce p (normalized bf16) into wave-private LDS
        {
            const unsigned short* kp = KbB + (size_t)(kbase + l15) * DDIM + hi * 8;
            const size_t r16 = (size_t)16 * DDIM;
            bf16x8_t c0 = *(const bf16x8_t*)kp;
            bf16x8_t c1 = *(const bf16x8_t*)(kp + 32);
            bf16x8_t c2 = *(const bf16x8_t*)(kp + r16);
            bf16x8_t c3 = *(const bf16x8_t*)(kp + r16 + 32);
#pragma unroll
            for (int cc = 0; cc < 4; ++cc) {    // 32 cols per step
                bf16x8_t n0 = c0, n1 = c1, n2 = c2, n3 = c3;
                if (cc < 3) {
                    const unsigned short* np = kp + (size_t)(cc + 1) * 32 * DDIM;
                    n0 = *(const bf16x8_t*)np;
                    n1 = *(const bf16x8_t*)(np + 32);
                    n2 = *(const bf16x8_t*)(np + r16);
                    n3 = *(const bf16x8_t*)(np + r16 + 32);
                }
                f32x4_t a0 = {0.f,0.f,0.f,0.f}, a1 = {0.f,0.f,0.f,0.f};
                a0 = __builtin_amdgcn_mfma_f32_16x16x32_bf16(aq0, c0, a0, 0, 0, 0);
                a0 = __builtin_amdgcn_mfma_f32_16x16x32_bf16(aq1, c1, a0, 0, 0, 0);
                a1 = __builtin_amdgcn_mfma_f32_16x16x32_bf16(aq0, c2, a1, 0, 0, 0);
                a1 = __builtin_amdgcn_mfma_f32_16x16x32_bf16(aq1, c3, a1, 0, 0, 0);
#pragma unroll
                for (int r = 0; r < 4; ++r) {
                    const int row = hi * 4 + r;
                    const int swz = row << 3;
                    const int col = cc * 32 + l15;
                    pw[row * KBLK + (col ^ swz)] =
                        f2bf(__builtin_amdgcn_exp2f(a0[r] - nlg[r]));
                    pw[row * KBLK + ((col + 16) ^ swz)] =
                        f2bf(__builtin_amdgcn_exp2f(a1[r] - nlg[r]));
                }
                c0 = n0; c1 = n1; c2 = n2; c3 = n3;
            }
        }

        // --- A-fragments (one read set serves all 4 d-tiles)
        const int aswz = l15 << 3;
        bf16x8_t af[4];
#pragma unroll
        for (int kc = 0; kc < 4; ++kc)
            af[kc] = *(const bf16x8_t*)&pw[l15 * KBLK + ((kc * 32 + hi * 8) ^ aswz)];

        // --- PV: 4 d-tiles, V rolling one tile ahead
#pragma unroll
        for (int dt = 0; dt < 4; ++dt) {
            bf16x8_t nv[4] = {bv[0], bv[1], bv[2], bv[3]};
            if (dt < 3) {
#pragma unroll
                for (int kc = 0; kc < 4; ++kc)
                    nv[kc] = *(const bf16x8_t*)
                        (vbase + (size_t)((dt + 1) * 16 + l15) * SDIM + kc * 32);
            }
#pragma unroll
            for (int kc = 0; kc < 4; ++kc)
                oacc[dt] = __builtin_amdgcn_mfma_f32_16x16x32_bf16(af[kc], bv[kc], oacc[dt], 0, 0, 0);
#pragma unroll
            for (int kc = 0; kc < 4; ++kc) bv[kc] = nv[kc];
        }

        // --- attn stores (coalesced f32x4, nontemporal)
#pragma unroll
        for (int j = 0; j < 8; ++j) {
            const int row2 = j * 2 + (lane >> 5);
            const int l31  = lane & 31;
            const short4_t pv4 =
                *(const short4_t*)&pw[row2 * KBLK + ((l31 * 4) ^ (row2 << 3))];
            f32x4_t o;
            o[0] = bf2f((unsigned short)pv4[0]);
            o[1] = bf2f((unsigned short)pv4[1]);
            o[2] = bf2f((unsigned short)pv4[2]);
            o[3] = bf2f((unsigned short)pv4[3]);
            __builtin_nontemporal_store(
                o, (f32x4_t*)(attnW + (size_t)row2 * SDIM + kbase + l31 * 4));
        }
    }

    // --- epilogue
#pragma unroll
    for (int dt = 0; dt < 4; ++dt) {
#pragma unroll
        for (int r = 0; r < 4; ++r)
            outW[(size_t)(hi * 4 + r) * DDIM + dt * 16 + l15] = oacc[dt][r];
    }
}

extern "C" void kernel_launch(void* const* d_in, const int* in_sizes, int n_in,
                              void* d_out, int out_size, void* d_ws, size_t ws_size,
                              hipStream_t stream) {
    const float* Q = (const float*)d_in[0];
    const float* K = (const float*)d_in[1];
    const float* V = (const float*)d_in[2];
    float* out  = (float*)d_out;
    float* attn = out + (size_t)NBH * SDIM * DDIM;

    unsigned short* Kb = (unsigned short*)d_ws;
    unsigned short* VT = Kb + (size_t)NBH * SDIM * DDIM;

    cvt_k_kernel<<<dim3((NBH * SDIM * DDIM) / (256 * 8)), dim3(256), 0, stream>>>(K, Kb);
    tr_v_kernel<<<dim3(NBH * 32), dim3(256), 0, stream>>>(V, VT);

    sdpa_main_kernel<<<dim3(NBH * 32), dim3(256), 0, stream>>>(Q, Kb, VT, out, attn);
}